// Round 1
// baseline (1112.783 us; speedup 1.0000x reference)
//
#include <hip/hip_runtime.h>
#include <float.h>

// VQVAE forward, MI355X. Inputs f32, output buffer f32, order [encoded |
// decoded | vq_loss]; harness compares after bf16-rounding both sides.
// KEY (R7 forensics): the np reference computes the VQ distances in FLOAT32
// including the shared ||z||^2 (~0.9) term -> near-ties quantize equal in
// f32 (ULP ~6e-8) and np.argmin tie-breaks FIRST-INDEX. This version
// emulates the np f32 pipeline bit-for-bit: f32 FMA convs (im2col tap order
// ci,ky,kx; bias post-add), numpy pairwise-32 sums, sequential-FMA dot,
// dist=(a+b_k)-2*m_k in f32, first-index argmin, enc = z + (z_q - z) in f32.
//
// R8 (this round): k_conv2vq was latency-bound (occupancy 11% from 100 KiB
// LDS -> 1 block/CU; VALUBusy 37%). All staged operands are WAVE-UNIFORM ->
// read them straight from global (const __restrict__, uniform index ->
// backend scalarizes to s_load; v_fma takes 1 SGPR src free). LDS dropped to
// 0; VQ k-loop 4-way unrolled (4 independent chains, per-chain FMA order
// unchanged); loss reduced via wave shuffle + f64 atomicAdd.
#pragma clang fp contract(off)
// (explicit fmaf() still emits hardware FMA; everything else stays per-op IEEE)

// numpy pairwise_sum for n=32: r[j]=a[j]; r[j]+=a[8+j]; +=a[16+j]; +=a[24+j];
// result = ((r0+r1)+(r2+r3))+((r4+r5)+(r6+r7))
__device__ __forceinline__ float pw32(const float* p) {
  float r0 = p[0], r1 = p[1], r2 = p[2], r3 = p[3];
  float r4 = p[4], r5 = p[5], r6 = p[6], r7 = p[7];
  r0 += p[8];  r1 += p[9];  r2 += p[10]; r3 += p[11];
  r4 += p[12]; r5 += p[13]; r6 += p[14]; r7 += p[15];
  r0 += p[16]; r1 += p[17]; r2 += p[18]; r3 += p[19];
  r4 += p[20]; r5 += p[21]; r6 += p[22]; r7 += p[23];
  r0 += p[24]; r1 += p[25]; r2 += p[26]; r3 += p[27];
  r4 += p[28]; r5 += p[29]; r6 += p[30]; r7 += p[31];
  return ((r0 + r1) + (r2 + r3)) + ((r4 + r5) + (r6 + r7));
}

// ---- prep: w2t[tap*32+co] = w2[co*256+tap]; bnG[k] = ||c_k||^2 (np pw32) ----
__global__ __launch_bounds__(256) void k_prep(
    const float* __restrict__ w2, const float* __restrict__ cb,
    float* __restrict__ w2t, float* __restrict__ bnG) {
  int t = threadIdx.x;
  for (int i = t; i < 8192; i += 256) {
    int tap = i >> 5, co = i & 31;
    w2t[i] = w2[co * 256 + tap];
  }
  for (int k = t; k < 512; k += 256) {
    float p[32];
    #pragma unroll
    for (int d = 0; d < 32; d++) { float c = cb[k * 32 + d]; p[d] = c * c; }
    bnG[k] = pw32(p);
  }
}

// ---- conv1: f32 FMA, taps (ci,r,c) ascending, bias post-add, relu ----
__global__ __launch_bounds__(256) void k_conv1(
    const float* __restrict__ img, const float* __restrict__ w1,
    const float* __restrict__ b1, float* __restrict__ h1, int b0) {
  __shared__ float w[768]; // (16,3,4,4)
  for (int i = threadIdx.x; i < 768; i += 256) w[i] = w1[i];
  __syncthreads();
  int idx = blockIdx.x * 256 + threadIdx.x;   // bl*2^18 + co*2^14 + y*2^7 + x
  int x  = idx & 127;
  int y  = (idx >> 7) & 127;
  int co = (idx >> 14) & 15;
  int bl = idx >> 18;
  const float* im = img + (long)(b0 + bl) * 196608;
  float a = 0.f;
  int iy0 = 2 * y - 1, ix0 = 2 * x - 1;
  for (int ci = 0; ci < 3; ci++) {
    const float* imc = im + ci * 65536;
    const float* wc  = w + co * 48 + ci * 16;
    for (int r = 0; r < 4; r++) {
      int iy = iy0 + r;
      if ((unsigned)iy >= 256u) continue;     // zero tap: fma(0,w,a)==a exact
      const float* row = imc + iy * 256;
      for (int c = 0; c < 4; c++) {
        int ix = ix0 + c;
        if ((unsigned)ix >= 256u) continue;
        a = fmaf(row[ix], wc[r * 4 + c], a);
      }
    }
  }
  a = a + b1[co];                              // bias added after conv (f32)
  h1[idx] = fmaxf(a, 0.f);
}

// ---- conv2 (f32 FMA) + relu + np-f32 VQ argmin + enc write + loss ----
// No LDS: w2t / cb / bnG / b2 accesses are wave-uniform -> scalar loads.
__global__ __launch_bounds__(256, 3) void k_conv2vq(
    const float* __restrict__ h1, const float* __restrict__ w2t,
    const float* __restrict__ b2, const float* __restrict__ cb,
    const float* __restrict__ bnG, float* __restrict__ enc,
    double* __restrict__ loss, int b0) {
  int t = threadIdx.x;
  int ppix = blockIdx.x * 256 + t;  // bl*4096 + y*64 + x
  int x  = ppix & 63;
  int y  = (ppix >> 6) & 63;
  int bl = ppix >> 12;
  int bg = b0 + bl;

  float z[32];
  #pragma unroll
  for (int q = 0; q < 32; q++) z[q] = 0.f;

  // taps (ci,r,c) ascending, f32 FMA per output channel (order == baseline)
  int iy0 = 2 * y - 1, ix0 = 2 * x - 1;
  for (int ci = 0; ci < 16; ci++) {
    long hbase = (long)bl * 262144 + (long)ci * 16384;
    for (int r = 0; r < 4; r++) {
      int iy = iy0 + r;
      if ((unsigned)iy >= 128u) continue;     // wave-uniform
      const float* hrow = h1 + hbase + (long)iy * 128;
      const float* wrow = w2t + ((ci * 16 + r * 4) << 5);
      for (int c = 0; c < 4; c++) {
        int ix = ix0 + c;
        float hv = ((unsigned)ix < 128u) ? hrow[ix] : 0.f;
        const float* wp = wrow + (c << 5);     // uniform -> s_load_dwordx16 x2
        #pragma unroll
        for (int co = 0; co < 32; co++)
          z[co] = fmaf(hv, wp[co], z[co]);
      }
    }
  }
  #pragma unroll
  for (int q = 0; q < 32; q++) {
    z[q] = z[q] + b2[q];                      // bias post-add
    z[q] = fmaxf(z[q], 0.f);                  // relu
  }

  // a = ||z||^2 via np pairwise-32 of f32 products
  float pz[32];
  #pragma unroll
  for (int d = 0; d < 32; d++) pz[d] = z[d] * z[d];
  float a = pw32(pz);

  // dist_k = (a + b_k) - 2*m_k, all f32; m_k = sequential FMA dot.
  // 4 k's in flight: chains independent, each chain's FMA order unchanged;
  // compares in ascending k with strict < == np first-index tie-break.
  float best = FLT_MAX; int bq = 0;
  for (int k = 0; k < 512; k += 4) {
    const float* c0 = cb + (k << 5);          // uniform -> scalar loads
    float m0 = 0.f, m1 = 0.f, m2 = 0.f, m3 = 0.f;
    #pragma unroll
    for (int d = 0; d < 32; d++) {
      m0 = fmaf(z[d], c0[d],      m0);
      m1 = fmaf(z[d], c0[32 + d], m1);
      m2 = fmaf(z[d], c0[64 + d], m2);
      m3 = fmaf(z[d], c0[96 + d], m3);
    }
    float d0 = (a + bnG[k])     - 2.0f * m0;
    float d1 = (a + bnG[k + 1]) - 2.0f * m1;
    float d2 = (a + bnG[k + 2]) - 2.0f * m2;
    float d3 = (a + bnG[k + 3]) - 2.0f * m3;
    if (d0 < best) { best = d0; bq = k; }
    if (d1 < best) { best = d1; bq = k + 1; }
    if (d2 < best) { best = d2; bq = k + 2; }
    if (d3 < best) { best = d3; bq = k + 3; }
  }

  double ls = 0.0;
  const float* cw = cb + (bq << 5);           // per-lane index (L2-hot)
  #pragma unroll
  for (int d = 0; d < 32; d++) {
    float df = cw[d] - z[d];                  // f32, as ref computes z_q - z
    float ev = z[d] + df;                     // straight-through forward value
    enc[(long)bg * 131072 + (long)d * 4096 + y * 64 + x] = ev;
    ls += (double)df * (double)df;
  }
  // wave-level f64 reduce (order-insensitive at double for bf16 compare)
  #pragma unroll
  for (int off = 32; off > 0; off >>= 1)
    ls += __shfl_down(ls, off, 64);
  if ((t & 63) == 0) atomicAdd(loss, ls);
}

// ---- deconv1: ConvT(32->16,k4,s2,p1)+relu, f32 ----
// LDS staged TRANSPOSED: wt[(co*16+ky*4+kx)*32 + ci] so the unrolled ci loop
// reads contiguous floats (8x ds_read_b128 instead of 32x ds_read_b32).
__global__ __launch_bounds__(256) void k_deconv1(
    const float* __restrict__ enc, const float* __restrict__ dw1,
    const float* __restrict__ db1, float* __restrict__ d1, int b0) {
  __shared__ float w[8192];
  for (int i = threadIdx.x; i < 8192; i += 256) {
    int ci = i & 31, rest = i >> 5;           // rest = co*16 + ky*4 + kx
    w[i] = dw1[ci * 256 + rest];
  }
  __syncthreads();
  int idx = blockIdx.x * 256 + threadIdx.x;   // bl*2^18 + co*2^14 + oy*2^7 + ox
  int ox = idx & 127;
  int oy = (idx >> 7) & 127;
  int co = (idx >> 14) & 15;
  int bl = idx >> 18;
  long ebase = (long)(b0 + bl) * 131072;
  float acc = 0.f;
  int iyt = (oy + 1) >> 1, ixt = (ox + 1) >> 1;
  for (int sy = 0; sy < 2; sy++) {
    int iy = iyt - sy;
    int ky = oy + 1 - 2 * iy;
    if ((unsigned)iy >= 64u || (unsigned)ky >= 4u) continue;
    for (int sx = 0; sx < 2; sx++) {
      int ix = ixt - sx;
      int kx = ox + 1 - 2 * ix;
      if ((unsigned)ix >= 64u || (unsigned)kx >= 4u) continue;
      const float* ep = enc + ebase + iy * 64 + ix;        // + ci*4096
      const float* wp = w + ((co * 16 + ky * 4 + kx) << 5); // + ci
      #pragma unroll
      for (int ci = 0; ci < 32; ci++)
        acc = fmaf(ep[ci * 4096], wp[ci], acc);  // same chain order as before
    }
  }
  acc = acc + db1[co];
  d1[idx] = fmaxf(acc, 0.f);
}

// ---- deconv2: ConvT(16->3,k4,s2,p1)+relu -> dec f32 ----
// Same transposed staging: wt[(co*16+ky*4+kx)*16 + ci].
__global__ __launch_bounds__(256) void k_deconv2(
    const float* __restrict__ d1, const float* __restrict__ dw2,
    const float* __restrict__ db2, float* __restrict__ dec, int b0) {
  __shared__ float w[768];
  for (int i = threadIdx.x; i < 768; i += 256) {
    int ci = i & 15, rest = i >> 4;           // rest = co*16 + ky*4 + kx
    w[i] = dw2[ci * 48 + rest];
  }
  __syncthreads();
  int idx = blockIdx.x * 256 + threadIdx.x;  // (bl*3+co)*65536 + oy*256 + ox
  int ox = idx & 255;
  int oy = (idx >> 8) & 255;
  int bc = idx >> 16;
  int co = bc % 3;
  int bl = bc / 3;
  int bg = b0 + bl;
  long dbase = (long)bl * 262144;
  float acc = 0.f;
  int iyt = (oy + 1) >> 1, ixt = (ox + 1) >> 1;
  for (int sy = 0; sy < 2; sy++) {
    int iy = iyt - sy;
    int ky = oy + 1 - 2 * iy;
    if ((unsigned)iy >= 128u || (unsigned)ky >= 4u) continue;
    for (int sx = 0; sx < 2; sx++) {
      int ix = ixt - sx;
      int kx = ox + 1 - 2 * ix;
      if ((unsigned)ix >= 128u || (unsigned)kx >= 4u) continue;
      const float* dp = d1 + dbase + (long)iy * 128 + ix;    // + ci*16384
      const float* wp = w + ((co * 16 + ky * 4 + kx) << 4);  // + ci
      #pragma unroll
      for (int ci = 0; ci < 16; ci++)
        acc = fmaf(dp[ci * 16384], wp[ci], acc);
    }
  }
  acc = acc + db2[co];
  dec[(long)(bg * 3 + co) * 65536 + oy * 256 + ox] = fmaxf(acc, 0.f);
}

__global__ void k_loss(const double* __restrict__ loss, float* __restrict__ out) {
  if (threadIdx.x == 0) out[0] = (float)(2.0 * loss[0] / 4194304.0);
}

extern "C" void kernel_launch(void* const* d_in, const int* in_sizes, int n_in,
                              void* d_out, int out_size, void* d_ws, size_t ws_size,
                              hipStream_t stream) {
  const float* imgs = (const float*)d_in[0];
  const float* w1   = (const float*)d_in[1];
  const float* b1   = (const float*)d_in[2];
  const float* w2   = (const float*)d_in[3];
  const float* b2   = (const float*)d_in[4];
  const float* cb   = (const float*)d_in[5];
  const float* dw1  = (const float*)d_in[6];
  const float* db1  = (const float*)d_in[7];
  const float* dw2  = (const float*)d_in[8];
  const float* db2  = (const float*)d_in[9];

  float* out = (float*)d_out;
  float* enc = out;               // (32,32,64,64)  f32
  float* dec = out + 4194304;     // (32,3,256,256) f32
  float* vql = out + 10485760;    // scalar         f32

  // workspace carve (from the top): loss(8) | bnG(2K) | w2t(32K) | h1/d1 below
  long ws = (long)ws_size;
  long top = (ws - 8) & ~7L;
  double* loss = (double*)((char*)d_ws + top);
  top = (top - 2048) & ~255L;
  float* bnG = (float*)((char*)d_ws + top);
  top = (top - 32768) & ~255L;
  float* w2t = (float*)((char*)d_ws + top);

  hipMemsetAsync(loss, 0, sizeof(double), stream);
  k_prep<<<1, 256, 0, stream>>>(w2, cb, w2t, bnG);

  // h1 / d1: f32, 1 MiB per image; batch-chunked through ws (below `top`)
  int cc = 1;
  for (int c = 32; c >= 1; c >>= 1)
    if ((long)c * 1048576 <= top) { cc = c; break; }

  float* h1 = (float*)d_ws;
  for (int b0 = 0; b0 < 32; b0 += cc) {
    k_conv1<<<cc * 1024, 256, 0, stream>>>(imgs, w1, b1, h1, b0);
    k_conv2vq<<<cc * 16, 256, 0, stream>>>(h1, w2t, b2, cb, bnG, enc, loss, b0);
  }

  float* d1 = (float*)d_ws;
  for (int b0 = 0; b0 < 32; b0 += cc) {
    k_deconv1<<<cc * 1024, 256, 0, stream>>>(enc, dw1, db1, d1, b0);
    k_deconv2<<<cc * 768, 256, 0, stream>>>(d1, dw2, db2, dec, b0);
  }

  k_loss<<<1, 64, 0, stream>>>(loss, vql);
}

// Round 2
// 662.017 us; speedup vs baseline: 1.6809x; 1.6809x over previous
//
#include <hip/hip_runtime.h>
#include <float.h>

// VQVAE forward, MI355X. Inputs f32, output buffer f32, order [encoded |
// decoded | vq_loss]; harness compares after bf16-rounding both sides.
// KEY (R7 forensics): the np reference computes the VQ distances in FLOAT32
// including the shared ||z||^2 (~0.9) term -> near-ties quantize equal in
// f32 (ULP ~6e-8) and np.argmin tie-breaks FIRST-INDEX. This version
// emulates the np f32 pipeline bit-for-bit: f32 FMA convs (im2col tap order
// ci,ky,kx; bias post-add), numpy pairwise-32 sums, sequential-FMA dot,
// dist=(a+b_k)-2*m_k in f32, first-index argmin, enc = z + (z_q - z) in f32.
//
// R8: conv2vq de-LDS'd (wave-uniform operands -> scalar loads), 4-way k
// unroll, shuffle loss reduce. Worked (conv2vq left the top-5).
// R9 (this round): R8's deconv1 "graft" regressed 4x -- VGPR fell to 44 and
// the 128 stride-16KB scalar global loads/thread (enc NCHW channel walk)
// went latency-serial (~11K cyc/wave). Structural fix: channel-contiguous
// intermediates. conv2vq also emits enc_t = NHWC copy of encoded (scratch
// inside the not-yet-written dec region of out; safe for any chunk size:
// m*cc*196608 <= 2097152 + m*cc*131072 for all m*cc <= 32). deconv1:
// thread = pixel, acc[16] over co, float4 enc_t reads, NHWC d1_t out.
// deconv2: float4 d1_t reads. FMA chain orders unchanged -> bit-identical.
#pragma clang fp contract(off)
// (explicit fmaf() still emits hardware FMA; everything else stays per-op IEEE)

// numpy pairwise_sum for n=32: r[j]=a[j]; r[j]+=a[8+j]; +=a[16+j]; +=a[24+j];
// result = ((r0+r1)+(r2+r3))+((r4+r5)+(r6+r7))
__device__ __forceinline__ float pw32(const float* p) {
  float r0 = p[0], r1 = p[1], r2 = p[2], r3 = p[3];
  float r4 = p[4], r5 = p[5], r6 = p[6], r7 = p[7];
  r0 += p[8];  r1 += p[9];  r2 += p[10]; r3 += p[11];
  r4 += p[12]; r5 += p[13]; r6 += p[14]; r7 += p[15];
  r0 += p[16]; r1 += p[17]; r2 += p[18]; r3 += p[19];
  r4 += p[20]; r5 += p[21]; r6 += p[22]; r7 += p[23];
  r0 += p[24]; r1 += p[25]; r2 += p[26]; r3 += p[27];
  r4 += p[28]; r5 += p[29]; r6 += p[30]; r7 += p[31];
  return ((r0 + r1) + (r2 + r3)) + ((r4 + r5) + (r6 + r7));
}

// ---- prep: w2t[tap*32+co] = w2[co*256+tap]; bnG[k] = ||c_k||^2 (np pw32) ----
__global__ __launch_bounds__(256) void k_prep(
    const float* __restrict__ w2, const float* __restrict__ cb,
    float* __restrict__ w2t, float* __restrict__ bnG) {
  int t = threadIdx.x;
  for (int i = t; i < 8192; i += 256) {
    int tap = i >> 5, co = i & 31;
    w2t[i] = w2[co * 256 + tap];
  }
  for (int k = t; k < 512; k += 256) {
    float p[32];
    #pragma unroll
    for (int d = 0; d < 32; d++) { float c = cb[k * 32 + d]; p[d] = c * c; }
    bnG[k] = pw32(p);
  }
}

// ---- conv1: f32 FMA, taps (ci,r,c) ascending, bias post-add, relu ----
__global__ __launch_bounds__(256) void k_conv1(
    const float* __restrict__ img, const float* __restrict__ w1,
    const float* __restrict__ b1, float* __restrict__ h1, int b0) {
  __shared__ float w[768]; // (16,3,4,4)
  for (int i = threadIdx.x; i < 768; i += 256) w[i] = w1[i];
  __syncthreads();
  int idx = blockIdx.x * 256 + threadIdx.x;   // bl*2^18 + co*2^14 + y*2^7 + x
  int x  = idx & 127;
  int y  = (idx >> 7) & 127;
  int co = (idx >> 14) & 15;
  int bl = idx >> 18;
  const float* im = img + (long)(b0 + bl) * 196608;
  float a = 0.f;
  int iy0 = 2 * y - 1, ix0 = 2 * x - 1;
  for (int ci = 0; ci < 3; ci++) {
    const float* imc = im + ci * 65536;
    const float* wc  = w + co * 48 + ci * 16;
    for (int r = 0; r < 4; r++) {
      int iy = iy0 + r;
      if ((unsigned)iy >= 256u) continue;     // zero tap: fma(0,w,a)==a exact
      const float* row = imc + iy * 256;
      for (int c = 0; c < 4; c++) {
        int ix = ix0 + c;
        if ((unsigned)ix >= 256u) continue;
        a = fmaf(row[ix], wc[r * 4 + c], a);
      }
    }
  }
  a = a + b1[co];                              // bias added after conv (f32)
  h1[idx] = fmaxf(a, 0.f);
}

// ---- conv2 (f32 FMA) + relu + np-f32 VQ argmin + enc/enc_t write + loss ----
// No LDS: w2t / cb / bnG / b2 accesses are wave-uniform -> scalar loads.
__global__ __launch_bounds__(256, 3) void k_conv2vq(
    const float* __restrict__ h1, const float* __restrict__ w2t,
    const float* __restrict__ b2, const float* __restrict__ cb,
    const float* __restrict__ bnG, float* __restrict__ enc,
    float* __restrict__ enct, double* __restrict__ loss, int b0) {
  int t = threadIdx.x;
  int ppix = blockIdx.x * 256 + t;  // bl*4096 + y*64 + x
  int x  = ppix & 63;
  int y  = (ppix >> 6) & 63;
  int bl = ppix >> 12;
  int bg = b0 + bl;

  float z[32];
  #pragma unroll
  for (int q = 0; q < 32; q++) z[q] = 0.f;

  // taps (ci,r,c) ascending, f32 FMA per output channel (order == baseline)
  int iy0 = 2 * y - 1, ix0 = 2 * x - 1;
  for (int ci = 0; ci < 16; ci++) {
    long hbase = (long)bl * 262144 + (long)ci * 16384;
    for (int r = 0; r < 4; r++) {
      int iy = iy0 + r;
      if ((unsigned)iy >= 128u) continue;     // wave-uniform
      const float* hrow = h1 + hbase + (long)iy * 128;
      const float* wrow = w2t + ((ci * 16 + r * 4) << 5);
      for (int c = 0; c < 4; c++) {
        int ix = ix0 + c;
        float hv = ((unsigned)ix < 128u) ? hrow[ix] : 0.f;
        const float* wp = wrow + (c << 5);     // uniform -> s_load_dwordx16 x2
        #pragma unroll
        for (int co = 0; co < 32; co++)
          z[co] = fmaf(hv, wp[co], z[co]);
      }
    }
  }
  #pragma unroll
  for (int q = 0; q < 32; q++) {
    z[q] = z[q] + b2[q];                      // bias post-add
    z[q] = fmaxf(z[q], 0.f);                  // relu
  }

  // a = ||z||^2 via np pairwise-32 of f32 products
  float pz[32];
  #pragma unroll
  for (int d = 0; d < 32; d++) pz[d] = z[d] * z[d];
  float a = pw32(pz);

  // dist_k = (a + b_k) - 2*m_k, all f32; m_k = sequential FMA dot.
  // 4 k's in flight: chains independent, each chain's FMA order unchanged;
  // compares in ascending k with strict < == np first-index tie-break.
  float best = FLT_MAX; int bq = 0;
  for (int k = 0; k < 512; k += 4) {
    const float* c0 = cb + (k << 5);          // uniform -> scalar loads
    float m0 = 0.f, m1 = 0.f, m2 = 0.f, m3 = 0.f;
    #pragma unroll
    for (int d = 0; d < 32; d++) {
      m0 = fmaf(z[d], c0[d],      m0);
      m1 = fmaf(z[d], c0[32 + d], m1);
      m2 = fmaf(z[d], c0[64 + d], m2);
      m3 = fmaf(z[d], c0[96 + d], m3);
    }
    float d0 = (a + bnG[k])     - 2.0f * m0;
    float d1 = (a + bnG[k + 1]) - 2.0f * m1;
    float d2 = (a + bnG[k + 2]) - 2.0f * m2;
    float d3 = (a + bnG[k + 3]) - 2.0f * m3;
    if (d0 < best) { best = d0; bq = k; }
    if (d1 < best) { best = d1; bq = k + 1; }
    if (d2 < best) { best = d2; bq = k + 2; }
    if (d3 < best) { best = d3; bq = k + 3; }
  }

  double ls = 0.0;
  const float* cw = cb + (bq << 5);           // per-lane index (L2-hot)
  long ebase = (long)bg * 131072 + y * 64 + x;
  float4* et4 = (float4*)(enct + ((long)bg * 4096 + y * 64 + x) * 32);
  #pragma unroll
  for (int d4 = 0; d4 < 8; d4++) {
    int d = d4 * 4;
    float f0 = cw[d + 0] - z[d + 0], e0 = z[d + 0] + f0;
    float f1 = cw[d + 1] - z[d + 1], e1 = z[d + 1] + f1;
    float f2 = cw[d + 2] - z[d + 2], e2 = z[d + 2] + f2;
    float f3 = cw[d + 3] - z[d + 3], e3 = z[d + 3] + f3;
    enc[ebase + (long)(d + 0) * 4096] = e0;
    enc[ebase + (long)(d + 1) * 4096] = e1;
    enc[ebase + (long)(d + 2) * 4096] = e2;
    enc[ebase + (long)(d + 3) * 4096] = e3;
    ls += (double)f0 * (double)f0;            // d-ascending, as before
    ls += (double)f1 * (double)f1;
    ls += (double)f2 * (double)f2;
    ls += (double)f3 * (double)f3;
    float4 v; v.x = e0; v.y = e1; v.z = e2; v.w = e3;
    et4[d4] = v;                              // NHWC copy for deconv1
  }
  // wave-level f64 reduce (order-insensitive at double for bf16 compare)
  #pragma unroll
  for (int off = 32; off > 0; off >>= 1)
    ls += __shfl_down(ls, off, 64);
  if ((t & 63) == 0) atomicAdd(loss, ls);
}

// ---- deconv1: ConvT(32->16,k4,s2,p1)+relu ----
// Thread = output pixel, acc[16] over all co (16 independent FMA chains).
// Reads enc_t NHWC (float4), writes d1_t NHWC (contiguous 64B per lane).
// Weights LDS [kk=16][ci=32][co=16]: per (combo,ci) a float4 over co; lanes
// differ only in kx parity -> 2-address broadcast (free per m136).
// Chain order per co: (sy,sx) outer, ci ascending == previous version.
__global__ __launch_bounds__(256) void k_deconv1(
    const float* __restrict__ enct, const float* __restrict__ dw1,
    const float* __restrict__ db1, float* __restrict__ d1t, int b0) {
  __shared__ float w[8192];
  for (int i = threadIdx.x; i < 8192; i += 256) {
    int co = i & 15, ci = (i >> 4) & 31, kk = i >> 9;
    w[i] = dw1[ci * 256 + co * 16 + kk];
  }
  __syncthreads();
  int idx = blockIdx.x * 256 + threadIdx.x;   // bl*16384 + oy*128 + ox
  int ox = idx & 127;
  int oy = (idx >> 7) & 127;
  int bl = idx >> 14;
  int bg = b0 + bl;
  float acc[16];
  #pragma unroll
  for (int q = 0; q < 16; q++) acc[q] = 0.f;
  int iyt = (oy + 1) >> 1, ixt = (ox + 1) >> 1;
  for (int sy = 0; sy < 2; sy++) {
    int iy = iyt - sy;
    int ky = oy + 1 - 2 * iy;                 // wave-uniform
    if ((unsigned)iy >= 64u || (unsigned)ky >= 4u) continue;
    for (int sx = 0; sx < 2; sx++) {
      int ix = ixt - sx;
      int kx = ox + 1 - 2 * ix;               // per-lane (parity)
      if ((unsigned)ix >= 64u || (unsigned)kx >= 4u) continue;
      const float4* ep4 =
          (const float4*)(enct + ((long)bg * 4096 + iy * 64 + ix) * 32);
      const float4* wl4 = (const float4*)(w + ((ky * 4 + kx) << 9));
      #pragma unroll
      for (int c4 = 0; c4 < 8; c4++) {
        float4 e = ep4[c4];
        #pragma unroll
        for (int j = 0; j < 4; j++) {
          float ev = (j == 0) ? e.x : (j == 1) ? e.y : (j == 2) ? e.z : e.w;
          int ci = c4 * 4 + j;
          #pragma unroll
          for (int q = 0; q < 4; q++) {
            float4 wv = wl4[ci * 4 + q];
            acc[q * 4 + 0] = fmaf(ev, wv.x, acc[q * 4 + 0]);
            acc[q * 4 + 1] = fmaf(ev, wv.y, acc[q * 4 + 1]);
            acc[q * 4 + 2] = fmaf(ev, wv.z, acc[q * 4 + 2]);
            acc[q * 4 + 3] = fmaf(ev, wv.w, acc[q * 4 + 3]);
          }
        }
      }
    }
  }
  float4* o4 = (float4*)(d1t + (long)idx * 16);
  #pragma unroll
  for (int q = 0; q < 4; q++) {
    float4 v;
    v.x = fmaxf(acc[q * 4 + 0] + db1[q * 4 + 0], 0.f);
    v.y = fmaxf(acc[q * 4 + 1] + db1[q * 4 + 1], 0.f);
    v.z = fmaxf(acc[q * 4 + 2] + db1[q * 4 + 2], 0.f);
    v.w = fmaxf(acc[q * 4 + 3] + db1[q * 4 + 3], 0.f);
    o4[q] = v;
  }
}

// ---- deconv2: ConvT(16->3,k4,s2,p1)+relu -> dec f32 ----
// Reads d1_t NHWC: per combo 4x float4 global + 4x b128 LDS + 16 FMA.
// Weights LDS [co=3][kk=16][ci=16] (ci contiguous); co block-uniform.
__global__ __launch_bounds__(256) void k_deconv2(
    const float* __restrict__ d1t, const float* __restrict__ dw2,
    const float* __restrict__ db2, float* __restrict__ dec, int b0) {
  __shared__ float w[768];
  for (int i = threadIdx.x; i < 768; i += 256) {
    int ci = i & 15, kk = (i >> 4) & 15, co = i >> 8;
    w[i] = dw2[ci * 48 + co * 16 + kk];
  }
  __syncthreads();
  int idx = blockIdx.x * 256 + threadIdx.x;  // (bl*3+co)*65536 + oy*256 + ox
  int ox = idx & 255;
  int oy = (idx >> 8) & 255;
  int bc = idx >> 16;
  int co = bc % 3;
  int bl = bc / 3;
  int bg = b0 + bl;
  float acc = 0.f;
  int iyt = (oy + 1) >> 1, ixt = (ox + 1) >> 1;
  for (int sy = 0; sy < 2; sy++) {
    int iy = iyt - sy;
    int ky = oy + 1 - 2 * iy;
    if ((unsigned)iy >= 128u || (unsigned)ky >= 4u) continue;
    for (int sx = 0; sx < 2; sx++) {
      int ix = ixt - sx;
      int kx = ox + 1 - 2 * ix;
      if ((unsigned)ix >= 128u || (unsigned)kx >= 4u) continue;
      const float4* dp4 =
          (const float4*)(d1t + ((long)bl * 16384 + iy * 128 + ix) * 16);
      const float4* wp4 = (const float4*)(w + ((co * 16 + ky * 4 + kx) << 4));
      #pragma unroll
      for (int c4 = 0; c4 < 4; c4++) {       // ci ascending == before
        float4 dv = dp4[c4];
        float4 wv = wp4[c4];
        acc = fmaf(dv.x, wv.x, acc);
        acc = fmaf(dv.y, wv.y, acc);
        acc = fmaf(dv.z, wv.z, acc);
        acc = fmaf(dv.w, wv.w, acc);
      }
    }
  }
  acc = acc + db2[co];
  dec[(long)(bg * 3 + co) * 65536 + oy * 256 + ox] = fmaxf(acc, 0.f);
}

__global__ void k_loss(const double* __restrict__ loss, float* __restrict__ out) {
  if (threadIdx.x == 0) out[0] = (float)(2.0 * loss[0] / 4194304.0);
}

extern "C" void kernel_launch(void* const* d_in, const int* in_sizes, int n_in,
                              void* d_out, int out_size, void* d_ws, size_t ws_size,
                              hipStream_t stream) {
  const float* imgs = (const float*)d_in[0];
  const float* w1   = (const float*)d_in[1];
  const float* b1   = (const float*)d_in[2];
  const float* w2   = (const float*)d_in[3];
  const float* b2   = (const float*)d_in[4];
  const float* cb   = (const float*)d_in[5];
  const float* dw1  = (const float*)d_in[6];
  const float* db1  = (const float*)d_in[7];
  const float* dw2  = (const float*)d_in[8];
  const float* db2  = (const float*)d_in[9];

  float* out = (float*)d_out;
  float* enc = out;               // (32,32,64,64)  f32
  float* dec = out + 4194304;     // (32,3,256,256) f32
  float* vql = out + 10485760;    // scalar         f32
  // enc_t (NHWC scratch, 16 MB) lives at the TAIL of the dec region; for
  // chunk m, dec written so far = m*cc*196608 floats <= 2097152 +
  // m*cc*131072 (enc_t still needed) since m*cc < 32. Stream-serialized.
  float* enct = dec + 2097152;

  // workspace carve (from the top): loss(8) | bnG(2K) | w2t(32K) | h1/d1t below
  long ws = (long)ws_size;
  long top = (ws - 8) & ~7L;
  double* loss = (double*)((char*)d_ws + top);
  top = (top - 2048) & ~255L;
  float* bnG = (float*)((char*)d_ws + top);
  top = (top - 32768) & ~255L;
  float* w2t = (float*)((char*)d_ws + top);

  hipMemsetAsync(loss, 0, sizeof(double), stream);
  k_prep<<<1, 256, 0, stream>>>(w2, cb, w2t, bnG);

  // h1 (encode) and d1_t (decode) alias: each cc MiB, chunked through ws
  int cc = 1;
  for (int c = 32; c >= 1; c >>= 1)
    if ((long)c * 1048576 <= top) { cc = c; break; }

  float* h1 = (float*)d_ws;
  for (int b0 = 0; b0 < 32; b0 += cc) {
    k_conv1<<<cc * 1024, 256, 0, stream>>>(imgs, w1, b1, h1, b0);
    k_conv2vq<<<cc * 16, 256, 0, stream>>>(h1, w2t, b2, cb, bnG, enc, enct,
                                           loss, b0);
  }

  float* d1t = (float*)d_ws;
  for (int b0 = 0; b0 < 32; b0 += cc) {
    k_deconv1<<<cc * 64, 256, 0, stream>>>(enct, dw1, db1, d1t, b0);
    k_deconv2<<<cc * 768, 256, 0, stream>>>(d1t, dw2, db2, dec, b0);
  }

  k_loss<<<1, 64, 0, stream>>>(loss, vql);
}